// Round 1
// 1000.622 us; speedup vs baseline: 1.1178x; 1.1178x over previous
//
#include <hip/hip_runtime.h>

#define N_TOK 16384
#define C_DIM 2048
#define E_NUM 16
#define DE_DIM 128
#define H_DIM 512

typedef __attribute__((ext_vector_type(8))) short bf16x8;
typedef __attribute__((ext_vector_type(4))) float f32x4;

__device__ __forceinline__ unsigned short f2bf(float f) {
    unsigned int u = __float_as_uint(f);
    unsigned int r = u + 0x7fffu + ((u >> 16) & 1u);   // round-to-nearest-even
    return (unsigned short)(r >> 16);
}

__device__ __forceinline__ uint4 pack8(float4 a, float4 b) {
    return make_uint4(
        (unsigned int)f2bf(a.x) | ((unsigned int)f2bf(a.y) << 16),
        (unsigned int)f2bf(a.z) | ((unsigned int)f2bf(a.w) << 16),
        (unsigned int)f2bf(b.x) | ((unsigned int)f2bf(b.y) << 16),
        (unsigned int)f2bf(b.z) | ((unsigned int)f2bf(b.w) << 16));
}

// exact-gelu via Abramowitz-Stegun 7.1.26 erf (|err| <= ~2e-7)
__device__ __forceinline__ float gelu_erf(float v) {
    float z  = v * 0.70710678118654752f;
    float az = fabsf(z);
    float t  = __builtin_amdgcn_rcpf(1.0f + 0.3275911f * az);
    float poly = t * (0.254829592f + t * (-0.284496736f + t * (1.421413741f +
                 t * (-1.453152027f + t * 1.061405429f))));
    float ex = __expf(-z * z);
    float er = copysignf(1.0f - poly * ex, z);
    return 0.5f * v * (1.0f + er);
}

// ---------------------------------------------------------------------------
// Kernel W: one-shot fp32 -> bf16 weight convert, PRE-SWIZZLED for bank-
// conflict-free LDS fragment reads after a LINEAR global_load_lds stage.
//   fcwb[e][h][ d ^ ((h&7)<<3) ] = bf16(fc_w[e][h][d])      (row = 256 B)
//   pjwb[e][d][ (h&~63) | ((h&63) ^ ((d&7)<<3)) ] = bf16(proj_w[e][d][h])
// grid = 512 x 256, each thread converts 8+8 elements.
// ---------------------------------------------------------------------------
__global__ __launch_bounds__(256) void moe_conv_w(
    const float* __restrict__ fcw, const float* __restrict__ pjw,
    unsigned short* __restrict__ fcwb, unsigned short* __restrict__ pjwb)
{
    const int id = blockIdx.x * 256 + threadIdx.x;   // 0..131071
    {
        const int base = id * 8;                     // flat idx into [16][512][128]
        const int d0 = base & 127;
        const int h  = (base >> 7) & 511;
        const int dd = d0 ^ ((h & 7) << 3);
        float4 a = *reinterpret_cast<const float4*>(fcw + base);
        float4 b = *reinterpret_cast<const float4*>(fcw + base + 4);
        *reinterpret_cast<uint4*>(fcwb + (base & ~127) + dd) = pack8(a, b);
    }
    {
        const int base = id * 8;                     // flat idx into [16][128][512]
        const int h0 = base & 511;
        const int d  = (base >> 9) & 127;
        const int hh = h0 ^ ((d & 7) << 3);          // stays within 64-chunk
        float4 a = *reinterpret_cast<const float4*>(pjw + base);
        float4 b = *reinterpret_cast<const float4*>(pjw + base + 4);
        *reinterpret_cast<uint4*>(pjwb + (base & ~511) + hh) = pack8(a, b);
    }
}

// ---------------------------------------------------------------------------
// Kernel A: gate logits (fp64 accum) + permute/convert x -> xp[e][n][128] bf16.
// v2: transposed data is accumulated in LDS (xpl) and flushed as COMPLETE
// 64B sectors (contiguous across lanes) instead of scattered 32B pieces.
// block = 256 threads, 32 tokens/block, grid = 512. LDS = 66.5 KB -> 2 blk/CU.
// ---------------------------------------------------------------------------
__global__ __launch_bounds__(256, 2) void moe_gate_permute(
    const float* __restrict__ xg,             // [N][2048] fp32
    const float* __restrict__ gw,             // [16][2048] fp32
    const float* __restrict__ gb,             // [16] fp32
    unsigned short* __restrict__ xp,          // [16][N][128] bf16 (if do_permute)
    float* __restrict__ gwf,                  // [N][16] float 0/1
    int do_permute)
{
    __shared__ float gws[16 * 256];           // gate_w chunk, 16 KiB
    __shared__ unsigned short xs[32 * 264];   // 32 tokens x 256-ch chunk bf16 (+8 pad)
    __shared__ unsigned int xpl[512 * 17];    // row=(n*16+e): 16 data dwords + 1 pad

    const int t  = threadIdx.x;
    const int n0 = blockIdx.x * 32;
    const int nl = t >> 3;     // token-local 0..31
    const int p  = t & 7;      // channel-slice 0..7

    double dacc[16];
#pragma unroll
    for (int e = 0; e < 16; ++e) dacc[e] = 0.0;

    for (int cc = 0; cc < 8; ++cc) {
        __syncthreads();   // protect gws/xs/xpl from previous iteration readers
        // stage gate_w chunk [16][256] into LDS (coalesced float4)
#pragma unroll
        for (int ii = 0; ii < 4; ++ii) {
            int fi = ii * 1024 + t * 4;
            int e = fi >> 8, cl = fi & 255;
            *reinterpret_cast<float4*>(&gws[e * 256 + cl]) =
                *reinterpret_cast<const float4*>(gw + (size_t)e * 2048 + cc * 256 + cl);
        }
        __syncthreads();
#pragma unroll
        for (int i = 0; i < 4; ++i) {
            const int cl = p * 8 + i * 64;          // channel within 256-chunk
            const float* xr = xg + (size_t)(n0 + nl) * 2048 + cc * 256 + cl;
            float4 xa = *reinterpret_cast<const float4*>(xr);
            float4 xb = *reinterpret_cast<const float4*>(xr + 4);
            double xd0 = xa.x, xd1 = xa.y, xd2 = xa.z, xd3 = xa.w;
            double xd4 = xb.x, xd5 = xb.y, xd6 = xb.z, xd7 = xb.w;
#pragma unroll
            for (int e = 0; e < 16; ++e) {
                float4 ga = *reinterpret_cast<const float4*>(&gws[e * 256 + cl]);
                float4 gv = *reinterpret_cast<const float4*>(&gws[e * 256 + cl + 4]);
                double s = dacc[e];
                s = fma(xd0, (double)ga.x, s);
                s = fma(xd1, (double)ga.y, s);
                s = fma(xd2, (double)ga.z, s);
                s = fma(xd3, (double)ga.w, s);
                s = fma(xd4, (double)gv.x, s);
                s = fma(xd5, (double)gv.y, s);
                s = fma(xd6, (double)gv.z, s);
                s = fma(xd7, (double)gv.w, s);
                dacc[e] = s;
            }
            if (do_permute) {
                unsigned int w0 = (unsigned int)f2bf(xa.x) | ((unsigned int)f2bf(xa.y) << 16);
                unsigned int w1 = (unsigned int)f2bf(xa.z) | ((unsigned int)f2bf(xa.w) << 16);
                unsigned int w2 = (unsigned int)f2bf(xb.x) | ((unsigned int)f2bf(xb.y) << 16);
                unsigned int w3 = (unsigned int)f2bf(xb.z) | ((unsigned int)f2bf(xb.w) << 16);
                *reinterpret_cast<uint4*>(&xs[nl * 264 + cl]) = make_uint4(w0, w1, w2, w3);
            }
        }
        if (do_permute) {
            __syncthreads();
            // transpose into xpl: row (n,e), d-pair dwords for this cc
#pragma unroll
            for (int rr = 0; rr < 2; ++rr) {
                const int rid = t + rr * 256;
                const int rn  = rid >> 4;
                const int re  = rid & 15;
                unsigned int* dst = &xpl[(rn * 16 + re) * 17 + (cc & 1) * 8];
#pragma unroll
                for (int k = 0; k < 8; ++k) {
                    unsigned int lo = xs[rn * 264 + (2 * k) * 16 + re];
                    unsigned int hi = xs[rn * 264 + (2 * k + 1) * 16 + re];
                    dst[k] = lo | (hi << 16);
                }
            }
            if (cc & 1) {
                __syncthreads();               // xpl quarter complete
                const int cp = cc >> 1;        // quarter: d in [cp*32, cp*32+32)
                // flush 512 rows x 64 B; 4 consecutive lanes = one full 64B sector
#pragma unroll
                for (int it = 0; it < 8; ++it) {
                    const int g = it * 256 + t;
                    const int e = g >> 7, n = (g >> 2) & 31, k = g & 3;
                    const int rb = (n * 16 + e) * 17 + k * 4;
                    uint4 v = make_uint4(xpl[rb], xpl[rb + 1], xpl[rb + 2], xpl[rb + 3]);
                    *reinterpret_cast<uint4*>(
                        xp + ((size_t)e * N_TOK + n0 + n) * 128 + cp * 32 + k * 8) = v;
                }
            }
        }
    }
    // reduce over the 8 p-lanes via xor-shuffle
#pragma unroll
    for (int e = 0; e < 16; ++e) {
        double v = dacc[e];
        v += __shfl_xor(v, 1);
        v += __shfl_xor(v, 2);
        v += __shfl_xor(v, 4);
        dacc[e] = v;
    }
    const int e0 = 2 * p;
    float g0 = (dacc[e0]     + (double)gb[e0]     > 0.0) ? 1.0f : 0.0f;
    float g1 = (dacc[e0 + 1] + (double)gb[e0 + 1] > 0.0) ? 1.0f : 0.0f;
    float2* gout = reinterpret_cast<float2*>(gwf + (size_t)(n0 + nl) * 16 + e0);
    *gout = make_float2(g0, g1);
}

// ---------------------------------------------------------------------------
// Kernel B: per-expert MLP, bf16 MFMA 16x16x32.
// PRE=1: pre-converted, pre-swizzled bf16 weights staged via global_load_lds
//        (no f2bf, no VGPR round-trip); XCD swizzle pins expert e to XCD e%8
//        so the 512 KB per-XCD weight set stays L2-resident.
// PRE=0: legacy fp32->bf16 staging (padded LDS layouts).
// ---------------------------------------------------------------------------
template<int PRE, int USEXP>
__global__ __launch_bounds__(256, 2) void moe_expert_mlp(
    const float* __restrict__ xg,             // [N][2048] fp32 (fallback path)
    const unsigned short* __restrict__ xp,    // [16][N][128] bf16
    const float* __restrict__ fcw,            // [16][512][128] fp32
    const float* __restrict__ fcb,            // [16][512] fp32
    const float* __restrict__ pjw,            // [16][128][512] fp32
    const float* __restrict__ pjb,            // [16][128] fp32
    const unsigned short* __restrict__ fcwb,  // [16][512][128] bf16 swizzled
    const unsigned short* __restrict__ pjwb,  // [16][128][512] bf16 swizzled
    const float* __restrict__ gwf,            // [N][16]
    float* __restrict__ y)                    // [N][2048] fp32
{
    __shared__ unsigned short W1s[64 * 136];       // PRE=1 uses linear [64][128]
    __shared__ unsigned short W2s[128 * 72];       // PRE=1 uses linear [128][64]
    __shared__ unsigned short Hs[4 * 32 * 72];     // per-wave [tok_local][hh_local]

    const int t    = threadIdx.x;
    const int wid  = t >> 6;
    const int lane = t & 63;
    const int q    = lane >> 4;
    const int m    = lane & 15;
    // XCD-aware swizzle: XCD = blockIdx.x % 8 -> expert e lands on XCD e%8
    const int raw = blockIdx.x;
    const int e   = (raw & 7) | (((raw >> 3) & 1) << 3);
    const int tb  = raw >> 4;
    const int n0  = tb * 128 + wid * 32;

    // A fragments for this wave's 32 tokens: A[m=lane&15][k=q*8+j]
    bf16x8 a1[2][4];
    if (USEXP) {
#pragma unroll
        for (int tm = 0; tm < 2; ++tm)
#pragma unroll
            for (int kk = 0; kk < 4; ++kk)
                a1[tm][kk] = *reinterpret_cast<const bf16x8*>(
                    xp + ((size_t)e * N_TOK + n0 + tm * 16 + m) * 128 + kk * 32 + q * 8);
    } else {
#pragma unroll
        for (int tm = 0; tm < 2; ++tm)
#pragma unroll
            for (int kk = 0; kk < 4; ++kk) {
                const float* base = xg + (size_t)(n0 + tm * 16 + m) * 2048
                                  + (kk * 32 + q * 8) * 16 + e;
                union { unsigned short u[8]; bf16x8 v; } pk;
#pragma unroll
                for (int j = 0; j < 8; ++j) pk.u[j] = f2bf(base[j * 16]);
                a1[tm][kk] = pk.v;
            }
    }

    f32x4 oacc[2][8];
#pragma unroll
    for (int tm = 0; tm < 2; ++tm)
#pragma unroll
        for (int tn = 0; tn < 8; ++tn) oacc[tm][tn] = (f32x4){0.f, 0.f, 0.f, 0.f};

    unsigned short* HsW = &Hs[wid * 32 * 72];
    const char* W1b = reinterpret_cast<const char*>(W1s);
    const char* W2b = reinterpret_cast<const char*>(W2s);

    for (int hc = 0; hc < 8; ++hc) {
        __syncthreads();   // previous chunk's weight readers done
        if constexpr (PRE) {
            // async linear stage of pre-swizzled bf16 weights (16 KB each)
            const unsigned short* g1 = fcwb + ((size_t)e * 512 + hc * 64) * 128;
            const unsigned short* g2 = pjwb + (size_t)e * 128 * 512 + hc * 64;
#pragma unroll
            for (int it = 0; it < 4; ++it) {
                const int s = it * 2048 + t * 8;
                __builtin_amdgcn_global_load_lds(
                    (const __attribute__((address_space(1))) unsigned int*)(g1 + s),
                    (__attribute__((address_space(3))) unsigned int*)(&W1s[s]), 16, 0, 0);
            }
#pragma unroll
            for (int it = 0; it < 4; ++it) {
                const int s = it * 2048 + t * 8;
                __builtin_amdgcn_global_load_lds(
                    (const __attribute__((address_space(1))) unsigned int*)
                        (g2 + (size_t)(s >> 6) * 512 + (s & 63)),
                    (__attribute__((address_space(3))) unsigned int*)(&W2s[s]), 16, 0, 0);
            }
        } else {
            // legacy: stage fc_w chunk fp32 -> bf16, padded layout
#pragma unroll
            for (int it = 0; it < 4; ++it) {
                int idx = it * 256 + t;
                int hh = idx >> 4, ds = (idx & 15) * 8;
                const float* src = fcw + ((size_t)e * 512 + hc * 64 + hh) * 128 + ds;
                float4 va = *reinterpret_cast<const float4*>(src);
                float4 vb = *reinterpret_cast<const float4*>(src + 4);
                *reinterpret_cast<uint4*>(&W1s[hh * 136 + ds]) = pack8(va, vb);
            }
#pragma unroll
            for (int it = 0; it < 4; ++it) {
                int idx = it * 256 + t;
                int d = idx >> 3, cs = (idx & 7) * 8;
                const float* src = pjw + ((size_t)e * 128 + d) * 512 + hc * 64 + cs;
                float4 va = *reinterpret_cast<const float4*>(src);
                float4 vb = *reinterpret_cast<const float4*>(src + 4);
                *reinterpret_cast<uint4*>(&W2s[d * 72 + cs]) = pack8(va, vb);
            }
        }
        __syncthreads();

        // GEMM1: H1[32 x 64] = Xe[32 x 128] * W1[128 x 64]
        f32x4 h1[2][4];
#pragma unroll
        for (int tm = 0; tm < 2; ++tm)
#pragma unroll
            for (int tn = 0; tn < 4; ++tn) h1[tm][tn] = (f32x4){0.f, 0.f, 0.f, 0.f};
#pragma unroll
        for (int kk = 0; kk < 4; ++kk) {
#pragma unroll
            for (int tn = 0; tn < 4; ++tn) {
                bf16x8 b;
                if constexpr (PRE) {
                    const int r = tn * 16 + m;
                    b = *reinterpret_cast<const bf16x8*>(
                        W1b + r * 256 + (((kk * 32 + q * 8) * 2) ^ ((r & 7) << 4)));
                } else {
                    b = *reinterpret_cast<const bf16x8*>(
                        &W1s[(tn * 16 + m) * 136 + kk * 32 + q * 8]);
                }
                h1[0][tn] = __builtin_amdgcn_mfma_f32_16x16x32_bf16(a1[0][kk], b, h1[0][tn], 0, 0, 0);
                h1[1][tn] = __builtin_amdgcn_mfma_f32_16x16x32_bf16(a1[1][kk], b, h1[1][tn], 0, 0, 0);
            }
        }
        // bias + gelu -> Hs (C/D layout: row = tm*16+q*4+r, col = tn*16+m)
#pragma unroll
        for (int tn = 0; tn < 4; ++tn) {
            float bias = fcb[e * 512 + hc * 64 + tn * 16 + m];
#pragma unroll
            for (int tm = 0; tm < 2; ++tm)
#pragma unroll
                for (int r = 0; r < 4; ++r) {
                    float g = gelu_erf(h1[tm][tn][r] + bias);
                    HsW[(tm * 16 + q * 4 + r) * 72 + tn * 16 + m] = f2bf(g);
                }
        }
        __asm__ volatile("" ::: "memory");  // order Hs writes before A2 reads

        // GEMM2: Oacc[32 x 128] += gelu(H1)[32 x 64] * W2[64 x 128]
#pragma unroll
        for (int kk2 = 0; kk2 < 2; ++kk2) {
            bf16x8 a2_0 = *reinterpret_cast<const bf16x8*>(&HsW[(m) * 72 + kk2 * 32 + q * 8]);
            bf16x8 a2_1 = *reinterpret_cast<const bf16x8*>(&HsW[(16 + m) * 72 + kk2 * 32 + q * 8]);
#pragma unroll
            for (int tn2 = 0; tn2 < 8; ++tn2) {
                bf16x8 b2;
                if constexpr (PRE) {
                    const int r2 = tn2 * 16 + m;
                    b2 = *reinterpret_cast<const bf16x8*>(
                        W2b + r2 * 128 + (((kk2 * 32 + q * 8) * 2) ^ ((r2 & 7) << 4)));
                } else {
                    b2 = *reinterpret_cast<const bf16x8*>(
                        &W2s[(tn2 * 16 + m) * 72 + kk2 * 32 + q * 8]);
                }
                oacc[0][tn2] = __builtin_amdgcn_mfma_f32_16x16x32_bf16(a2_0, b2, oacc[0][tn2], 0, 0, 0);
                oacc[1][tn2] = __builtin_amdgcn_mfma_f32_16x16x32_bf16(a2_1, b2, oacc[1][tn2], 0, 0, 0);
            }
        }
    }

    // epilogue: (acc + proj_b) * gate, store FP32 at y[n][e*128 + d]
    float gwv[2][4];
#pragma unroll
    for (int tm = 0; tm < 2; ++tm)
#pragma unroll
        for (int r = 0; r < 4; ++r)
            gwv[tm][r] = gwf[(size_t)(n0 + tm * 16 + q * 4 + r) * 16 + e];
#pragma unroll
    for (int tn2 = 0; tn2 < 8; ++tn2) {
        float pb = pjb[e * 128 + tn2 * 16 + m];
#pragma unroll
        for (int tm = 0; tm < 2; ++tm)
#pragma unroll
            for (int r = 0; r < 4; ++r) {
                float v = (oacc[tm][tn2][r] + pb) * gwv[tm][r];
                y[(size_t)(n0 + tm * 16 + q * 4 + r) * 2048 + e * 128 + tn2 * 16 + m] = v;
            }
    }
}

extern "C" void kernel_launch(void* const* d_in, const int* in_sizes, int n_in,
                              void* d_out, int out_size, void* d_ws, size_t ws_size,
                              hipStream_t stream) {
    const float* x      = (const float*)d_in[0];
    const float* gate_w = (const float*)d_in[1];
    const float* gate_b = (const float*)d_in[2];
    const float* fc_w   = (const float*)d_in[3];
    const float* fc_b   = (const float*)d_in[4];
    const float* proj_w = (const float*)d_in[5];
    const float* proj_b = (const float*)d_in[6];
    float* y            = (float*)d_out;

    // ws layout: gwf (1 MiB) | xp (64 MiB) | fcwb (2 MiB) | pjwb (2 MiB)
    const size_t gwf_bytes = (size_t)N_TOK * E_NUM * 4;
    const size_t xp_bytes  = (size_t)E_NUM * N_TOK * DE_DIM * 2;
    const size_t wb_bytes  = (size_t)E_NUM * H_DIM * DE_DIM * 2;
    float* gwf = (float*)d_ws;
    unsigned short* xp   = (unsigned short*)((char*)d_ws + gwf_bytes);
    unsigned short* fcwb = (unsigned short*)((char*)d_ws + gwf_bytes + xp_bytes);
    unsigned short* pjwb = (unsigned short*)((char*)d_ws + gwf_bytes + xp_bytes + wb_bytes);
    const int use_xp  = (ws_size >= gwf_bytes + xp_bytes) ? 1 : 0;
    const int use_pre = (ws_size >= gwf_bytes + xp_bytes + 2 * wb_bytes) ? 1 : 0;

    if (use_pre)
        moe_conv_w<<<dim3(512), dim3(256), 0, stream>>>(fc_w, proj_w, fcwb, pjwb);
    moe_gate_permute<<<dim3(N_TOK / 32), dim3(256), 0, stream>>>(
        x, gate_w, gate_b, xp, gwf, use_xp);
    if (use_pre)
        moe_expert_mlp<1, 1><<<dim3(E_NUM * (N_TOK / 128)), dim3(256), 0, stream>>>(
            x, xp, fc_w, fc_b, proj_w, proj_b, fcwb, pjwb, gwf, y);
    else if (use_xp)
        moe_expert_mlp<0, 1><<<dim3(E_NUM * (N_TOK / 128)), dim3(256), 0, stream>>>(
            x, xp, fc_w, fc_b, proj_w, proj_b, fcwb, pjwb, gwf, y);
    else
        moe_expert_mlp<0, 0><<<dim3(E_NUM * (N_TOK / 128)), dim3(256), 0, stream>>>(
            x, xp, fc_w, fc_b, proj_w, proj_b, fcwb, pjwb, gwf, y);
}

// Round 2
// 452.284 us; speedup vs baseline: 2.4731x; 2.2124x over previous
//
#include <hip/hip_runtime.h>

#define N_TOK 16384
#define C_DIM 2048
#define E_NUM 16
#define DE_DIM 128
#define H_DIM 512

typedef __attribute__((ext_vector_type(8))) short bf16x8;
typedef __attribute__((ext_vector_type(4))) float f32x4;

__device__ __forceinline__ unsigned short f2bf(float f) {
    unsigned int u = __float_as_uint(f);
    unsigned int r = u + 0x7fffu + ((u >> 16) & 1u);   // round-to-nearest-even
    return (unsigned short)(r >> 16);
}

__device__ __forceinline__ uint4 pack8(float4 a, float4 b) {
    return make_uint4(
        (unsigned int)f2bf(a.x) | ((unsigned int)f2bf(a.y) << 16),
        (unsigned int)f2bf(a.z) | ((unsigned int)f2bf(a.w) << 16),
        (unsigned int)f2bf(b.x) | ((unsigned int)f2bf(b.y) << 16),
        (unsigned int)f2bf(b.z) | ((unsigned int)f2bf(b.w) << 16));
}

// exact-gelu via Abramowitz-Stegun 7.1.26 erf (|err| <= ~2e-7)
__device__ __forceinline__ float gelu_erf(float v) {
    float z  = v * 0.70710678118654752f;
    float az = fabsf(z);
    float t  = __builtin_amdgcn_rcpf(1.0f + 0.3275911f * az);
    float poly = t * (0.254829592f + t * (-0.284496736f + t * (1.421413741f +
                 t * (-1.453152027f + t * 1.061405429f))));
    float ex = __expf(-z * z);
    float er = copysignf(1.0f - poly * ex, z);
    return 0.5f * v * (1.0f + er);
}

// ---------------------------------------------------------------------------
// Kernel W: one-shot fp32 -> bf16 weight convert, PRE-SWIZZLED for bank-
// conflict-free LDS fragment reads after a LINEAR global_load_lds stage.
//   fcwb[e][h][ d ^ ((h&7)<<3) ] = bf16(fc_w[e][h][d])      (row = 256 B)
//   pjwb[e][d][ (h&~63) | ((h&63) ^ ((d&7)<<3)) ] = bf16(proj_w[e][d][h])
// ---------------------------------------------------------------------------
__global__ __launch_bounds__(256) void moe_conv_w(
    const float* __restrict__ fcw, const float* __restrict__ pjw,
    unsigned short* __restrict__ fcwb, unsigned short* __restrict__ pjwb)
{
    const int id = blockIdx.x * 256 + threadIdx.x;   // 0..131071
    {
        const int base = id * 8;                     // flat idx into [16][512][128]
        const int d0 = base & 127;
        const int h  = (base >> 7) & 511;
        const int dd = d0 ^ ((h & 7) << 3);
        float4 a = *reinterpret_cast<const float4*>(fcw + base);
        float4 b = *reinterpret_cast<const float4*>(fcw + base + 4);
        *reinterpret_cast<uint4*>(fcwb + (base & ~127) + dd) = pack8(a, b);
    }
    {
        const int base = id * 8;                     // flat idx into [16][128][512]
        const int h0 = base & 511;
        const int d  = (base >> 9) & 127;
        const int hh = h0 ^ ((d & 7) << 3);          // stays within 64-chunk
        float4 a = *reinterpret_cast<const float4*>(pjw + base);
        float4 b = *reinterpret_cast<const float4*>(pjw + base + 4);
        *reinterpret_cast<uint4*>(pjwb + (base & ~511) + hh) = pack8(a, b);
    }
}

// ---------------------------------------------------------------------------
// Kernel A: gate logits ONLY (fp64-exact products, fp64 accum -> sign bit).
// The permute/xp intermediate is gone: kernel B gathers x directly.
// block = 256 threads (token nl = t>>3, channel-slice p = t&7), grid = 512.
// Math/loop order is instruction-identical to the previous verified version
// so gate decisions stay bit-identical.
// ---------------------------------------------------------------------------
__global__ __launch_bounds__(256) void moe_gate(
    const float* __restrict__ xg,             // [N][2048] fp32
    const float* __restrict__ gw,             // [16][2048] fp32
    const float* __restrict__ gb,             // [16] fp32
    float* __restrict__ gwf)                  // [N][16] float 0/1
{
    __shared__ float gws[16 * 256];           // gate_w chunk, 16 KiB

    const int t  = threadIdx.x;
    const int n0 = blockIdx.x * 32;
    const int nl = t >> 3;     // token-local 0..31
    const int p  = t & 7;      // channel-slice 0..7

    double dacc[16];
#pragma unroll
    for (int e = 0; e < 16; ++e) dacc[e] = 0.0;

    for (int cc = 0; cc < 8; ++cc) {
        __syncthreads();   // protect gws from previous iteration readers
#pragma unroll
        for (int ii = 0; ii < 4; ++ii) {
            int fi = ii * 1024 + t * 4;
            int e = fi >> 8, cl = fi & 255;
            *reinterpret_cast<float4*>(&gws[e * 256 + cl]) =
                *reinterpret_cast<const float4*>(gw + (size_t)e * 2048 + cc * 256 + cl);
        }
        __syncthreads();
#pragma unroll
        for (int i = 0; i < 4; ++i) {
            const int cl = p * 8 + i * 64;          // channel within 256-chunk
            const float* xr = xg + (size_t)(n0 + nl) * 2048 + cc * 256 + cl;
            float4 xa = *reinterpret_cast<const float4*>(xr);
            float4 xb = *reinterpret_cast<const float4*>(xr + 4);
            double xd0 = xa.x, xd1 = xa.y, xd2 = xa.z, xd3 = xa.w;
            double xd4 = xb.x, xd5 = xb.y, xd6 = xb.z, xd7 = xb.w;
#pragma unroll
            for (int e = 0; e < 16; ++e) {
                float4 ga = *reinterpret_cast<const float4*>(&gws[e * 256 + cl]);
                float4 gv = *reinterpret_cast<const float4*>(&gws[e * 256 + cl + 4]);
                double s = dacc[e];
                s = fma(xd0, (double)ga.x, s);
                s = fma(xd1, (double)ga.y, s);
                s = fma(xd2, (double)ga.z, s);
                s = fma(xd3, (double)ga.w, s);
                s = fma(xd4, (double)gv.x, s);
                s = fma(xd5, (double)gv.y, s);
                s = fma(xd6, (double)gv.z, s);
                s = fma(xd7, (double)gv.w, s);
                dacc[e] = s;
            }
        }
    }
    // reduce over the 8 p-lanes (contiguous lane bits 0..2) via xor-shuffle
#pragma unroll
    for (int e = 0; e < 16; ++e) {
        double v = dacc[e];
        v += __shfl_xor(v, 1);
        v += __shfl_xor(v, 2);
        v += __shfl_xor(v, 4);
        dacc[e] = v;
    }
    const int e0 = 2 * p;
    float g0 = (dacc[e0]     + (double)gb[e0]     > 0.0) ? 1.0f : 0.0f;
    float g1 = (dacc[e0 + 1] + (double)gb[e0 + 1] > 0.0) ? 1.0f : 0.0f;
    float2* gout = reinterpret_cast<float2*>(gwf + (size_t)(n0 + nl) * 16 + e0);
    *gout = make_float2(g0, g1);
}

// ---------------------------------------------------------------------------
// Kernel B: per-expert MLP, bf16 MFMA 16x16x32. A-operand gathered DIRECTLY
// from x (4B loads at 64B stride) — the 16 e-blocks sharing a token-block are
// pinned to one XCD (tb-pinned bijective swizzle) so x lines are fetched once
// per XCD L2 and reused 16x.
// PRE=1: pre-converted, pre-swizzled bf16 weights staged via global_load_lds.
// PRE=0: legacy fp32->bf16 staging (small-workspace fallback).
// ---------------------------------------------------------------------------
template<int PRE>
__global__ __launch_bounds__(256, 2) void moe_expert_mlp(
    const float* __restrict__ xg,             // [N][2048] fp32
    const float* __restrict__ fcw,            // [16][512][128] fp32
    const float* __restrict__ fcb,            // [16][512] fp32
    const float* __restrict__ pjw,            // [16][128][512] fp32
    const float* __restrict__ pjb,            // [16][128] fp32
    const unsigned short* __restrict__ fcwb,  // [16][512][128] bf16 swizzled
    const unsigned short* __restrict__ pjwb,  // [16][128][512] bf16 swizzled
    const float* __restrict__ gwf,            // [N][16]
    float* __restrict__ y)                    // [N][2048] fp32
{
    __shared__ unsigned short W1s[64 * 136];       // PRE=1 uses linear [64][128]
    __shared__ unsigned short W2s[128 * 72];       // PRE=1 uses linear [128][64]
    __shared__ unsigned short Hs[4 * 32 * 72];     // per-wave [tok_local][hh_local]

    const int t    = threadIdx.x;
    const int wid  = t >> 6;
    const int lane = t & 63;
    const int q    = lane >> 4;
    const int m    = lane & 15;
    // tb-pinned bijective XCD swizzle: raw = (hi:4)(e:4)(lo:3)
    //   XCD = raw&7; e is the fast slot index -> 16 e-blocks of one tb are
    //   consecutive slots on the SAME XCD -> x lines reused 16x in that L2.
    const int raw = blockIdx.x;
    const int e   = (raw >> 3) & 15;
    const int tb  = (raw & 7) | ((raw >> 7) << 3);
    const int n0  = tb * 128 + wid * 32;

    // A fragments for this wave's 32 tokens: A[m=lane&15][k=q*8+j]
    // gathered from x: channel of (e, d) is d*16 + e
    bf16x8 a1[2][4];
#pragma unroll
    for (int tm = 0; tm < 2; ++tm)
#pragma unroll
        for (int kk = 0; kk < 4; ++kk) {
            const float* base = xg + (size_t)(n0 + tm * 16 + m) * 2048
                              + (kk * 32 + q * 8) * 16 + e;
            union { unsigned short u[8]; bf16x8 v; } pk;
#pragma unroll
            for (int j = 0; j < 8; ++j) pk.u[j] = f2bf(base[j * 16]);
            a1[tm][kk] = pk.v;
        }

    f32x4 oacc[2][8];
#pragma unroll
    for (int tm = 0; tm < 2; ++tm)
#pragma unroll
        for (int tn = 0; tn < 8; ++tn) oacc[tm][tn] = (f32x4){0.f, 0.f, 0.f, 0.f};

    unsigned short* HsW = &Hs[wid * 32 * 72];
    const char* W1b = reinterpret_cast<const char*>(W1s);
    const char* W2b = reinterpret_cast<const char*>(W2s);

    for (int hc = 0; hc < 8; ++hc) {
        __syncthreads();   // previous chunk's weight readers done
        if constexpr (PRE) {
            // async linear stage of pre-swizzled bf16 weights (16 KB each)
            const unsigned short* g1 = fcwb + ((size_t)e * 512 + hc * 64) * 128;
            const unsigned short* g2 = pjwb + (size_t)e * 128 * 512 + hc * 64;
#pragma unroll
            for (int it = 0; it < 4; ++it) {
                const int s = it * 2048 + t * 8;
                __builtin_amdgcn_global_load_lds(
                    (const __attribute__((address_space(1))) unsigned int*)(g1 + s),
                    (__attribute__((address_space(3))) unsigned int*)(&W1s[s]), 16, 0, 0);
            }
#pragma unroll
            for (int it = 0; it < 4; ++it) {
                const int s = it * 2048 + t * 8;
                __builtin_amdgcn_global_load_lds(
                    (const __attribute__((address_space(1))) unsigned int*)
                        (g2 + (size_t)(s >> 6) * 512 + (s & 63)),
                    (__attribute__((address_space(3))) unsigned int*)(&W2s[s]), 16, 0, 0);
            }
        } else {
            // legacy: stage fc_w chunk fp32 -> bf16, padded layout
#pragma unroll
            for (int it = 0; it < 4; ++it) {
                int idx = it * 256 + t;
                int hh = idx >> 4, ds = (idx & 15) * 8;
                const float* src = fcw + ((size_t)e * 512 + hc * 64 + hh) * 128 + ds;
                float4 va = *reinterpret_cast<const float4*>(src);
                float4 vb = *reinterpret_cast<const float4*>(src + 4);
                *reinterpret_cast<uint4*>(&W1s[hh * 136 + ds]) = pack8(va, vb);
            }
#pragma unroll
            for (int it = 0; it < 4; ++it) {
                int idx = it * 256 + t;
                int d = idx >> 3, cs = (idx & 7) * 8;
                const float* src = pjw + ((size_t)e * 128 + d) * 512 + hc * 64 + cs;
                float4 va = *reinterpret_cast<const float4*>(src);
                float4 vb = *reinterpret_cast<const float4*>(src + 4);
                *reinterpret_cast<uint4*>(&W2s[d * 72 + cs]) = pack8(va, vb);
            }
        }
        __syncthreads();

        // GEMM1: H1[32 x 64] = Xe[32 x 128] * W1[128 x 64]
        f32x4 h1[2][4];
#pragma unroll
        for (int tm = 0; tm < 2; ++tm)
#pragma unroll
            for (int tn = 0; tn < 4; ++tn) h1[tm][tn] = (f32x4){0.f, 0.f, 0.f, 0.f};
#pragma unroll
        for (int kk = 0; kk < 4; ++kk) {
#pragma unroll
            for (int tn = 0; tn < 4; ++tn) {
                bf16x8 b;
                if constexpr (PRE) {
                    const int r = tn * 16 + m;
                    b = *reinterpret_cast<const bf16x8*>(
                        W1b + r * 256 + (((kk * 32 + q * 8) * 2) ^ ((r & 7) << 4)));
                } else {
                    b = *reinterpret_cast<const bf16x8*>(
                        &W1s[(tn * 16 + m) * 136 + kk * 32 + q * 8]);
                }
                h1[0][tn] = __builtin_amdgcn_mfma_f32_16x16x32_bf16(a1[0][kk], b, h1[0][tn], 0, 0, 0);
                h1[1][tn] = __builtin_amdgcn_mfma_f32_16x16x32_bf16(a1[1][kk], b, h1[1][tn], 0, 0, 0);
            }
        }
        // bias + gelu -> Hs (C/D layout: row = tm*16+q*4+r, col = tn*16+m)
#pragma unroll
        for (int tn = 0; tn < 4; ++tn) {
            float bias = fcb[e * 512 + hc * 64 + tn * 16 + m];
#pragma unroll
            for (int tm = 0; tm < 2; ++tm)
#pragma unroll
                for (int r = 0; r < 4; ++r) {
                    float g = gelu_erf(h1[tm][tn][r] + bias);
                    HsW[(tm * 16 + q * 4 + r) * 72 + tn * 16 + m] = f2bf(g);
                }
        }
        __asm__ volatile("" ::: "memory");  // order Hs writes before A2 reads

        // GEMM2: Oacc[32 x 128] += gelu(H1)[32 x 64] * W2[64 x 128]
#pragma unroll
        for (int kk2 = 0; kk2 < 2; ++kk2) {
            bf16x8 a2_0 = *reinterpret_cast<const bf16x8*>(&HsW[(m) * 72 + kk2 * 32 + q * 8]);
            bf16x8 a2_1 = *reinterpret_cast<const bf16x8*>(&HsW[(16 + m) * 72 + kk2 * 32 + q * 8]);
#pragma unroll
            for (int tn2 = 0; tn2 < 8; ++tn2) {
                bf16x8 b2;
                if constexpr (PRE) {
                    const int r2 = tn2 * 16 + m;
                    b2 = *reinterpret_cast<const bf16x8*>(
                        W2b + r2 * 128 + (((kk2 * 32 + q * 8) * 2) ^ ((r2 & 7) << 4)));
                } else {
                    b2 = *reinterpret_cast<const bf16x8*>(
                        &W2s[(tn2 * 16 + m) * 72 + kk2 * 32 + q * 8]);
                }
                oacc[0][tn2] = __builtin_amdgcn_mfma_f32_16x16x32_bf16(a2_0, b2, oacc[0][tn2], 0, 0, 0);
                oacc[1][tn2] = __builtin_amdgcn_mfma_f32_16x16x32_bf16(a2_1, b2, oacc[1][tn2], 0, 0, 0);
            }
        }
    }

    // epilogue: (acc + proj_b) * gate, store FP32 at y[n][e*128 + d]
    float gwv[2][4];
#pragma unroll
    for (int tm = 0; tm < 2; ++tm)
#pragma unroll
        for (int r = 0; r < 4; ++r)
            gwv[tm][r] = gwf[(size_t)(n0 + tm * 16 + q * 4 + r) * 16 + e];
#pragma unroll
    for (int tn2 = 0; tn2 < 8; ++tn2) {
        float pb = pjb[e * 128 + tn2 * 16 + m];
#pragma unroll
        for (int tm = 0; tm < 2; ++tm)
#pragma unroll
            for (int r = 0; r < 4; ++r) {
                float v = (oacc[tm][tn2][r] + pb) * gwv[tm][r];
                y[(size_t)(n0 + tm * 16 + q * 4 + r) * 2048 + e * 128 + tn2 * 16 + m] = v;
            }
    }
}

extern "C" void kernel_launch(void* const* d_in, const int* in_sizes, int n_in,
                              void* d_out, int out_size, void* d_ws, size_t ws_size,
                              hipStream_t stream) {
    const float* x      = (const float*)d_in[0];
    const float* gate_w = (const float*)d_in[1];
    const float* gate_b = (const float*)d_in[2];
    const float* fc_w   = (const float*)d_in[3];
    const float* fc_b   = (const float*)d_in[4];
    const float* proj_w = (const float*)d_in[5];
    const float* proj_b = (const float*)d_in[6];
    float* y            = (float*)d_out;

    // ws layout: gwf (1 MiB) | fcwb (2 MiB) | pjwb (2 MiB)
    const size_t gwf_bytes = (size_t)N_TOK * E_NUM * 4;
    const size_t wb_bytes  = (size_t)E_NUM * H_DIM * DE_DIM * 2;
    float* gwf = (float*)d_ws;
    unsigned short* fcwb = (unsigned short*)((char*)d_ws + gwf_bytes);
    unsigned short* pjwb = (unsigned short*)((char*)d_ws + gwf_bytes + wb_bytes);
    const int use_pre = (ws_size >= gwf_bytes + 2 * wb_bytes) ? 1 : 0;

    if (use_pre)
        moe_conv_w<<<dim3(512), dim3(256), 0, stream>>>(fc_w, proj_w, fcwb, pjwb);
    moe_gate<<<dim3(N_TOK / 32), dim3(256), 0, stream>>>(x, gate_w, gate_b, gwf);
    if (use_pre)
        moe_expert_mlp<1><<<dim3(E_NUM * (N_TOK / 128)), dim3(256), 0, stream>>>(
            x, fc_w, fc_b, proj_w, proj_b, fcwb, pjwb, gwf, y);
    else
        moe_expert_mlp<0><<<dim3(E_NUM * (N_TOK / 128)), dim3(256), 0, stream>>>(
            x, fc_w, fc_b, proj_w, proj_b, fcwb, pjwb, gwf, y);
}

// Round 3
// 452.028 us; speedup vs baseline: 2.4745x; 1.0006x over previous
//
#include <hip/hip_runtime.h>

#define N_TOK 16384
#define C_DIM 2048
#define E_NUM 16
#define DE_DIM 128
#define H_DIM 512

typedef __attribute__((ext_vector_type(8))) short bf16x8;
typedef __attribute__((ext_vector_type(4))) float f32x4;

__device__ __forceinline__ unsigned short f2bf(float f) {
    unsigned int u = __float_as_uint(f);
    unsigned int r = u + 0x7fffu + ((u >> 16) & 1u);   // round-to-nearest-even
    return (unsigned short)(r >> 16);
}

__device__ __forceinline__ uint4 pack8(float4 a, float4 b) {
    return make_uint4(
        (unsigned int)f2bf(a.x) | ((unsigned int)f2bf(a.y) << 16),
        (unsigned int)f2bf(a.z) | ((unsigned int)f2bf(a.w) << 16),
        (unsigned int)f2bf(b.x) | ((unsigned int)f2bf(b.y) << 16),
        (unsigned int)f2bf(b.z) | ((unsigned int)f2bf(b.w) << 16));
}

// exact-gelu via Abramowitz-Stegun 7.1.26 erf (|err| <= ~2e-7)
__device__ __forceinline__ float gelu_erf(float v) {
    float z  = v * 0.70710678118654752f;
    float az = fabsf(z);
    float t  = __builtin_amdgcn_rcpf(1.0f + 0.3275911f * az);
    float poly = t * (0.254829592f + t * (-0.284496736f + t * (1.421413741f +
                 t * (-1.453152027f + t * 1.061405429f))));
    float ex = __expf(-z * z);
    float er = copysignf(1.0f - poly * ex, z);
    return 0.5f * v * (1.0f + er);
}

// ---------------------------------------------------------------------------
// Kernel W: one-shot fp32 -> bf16 weight convert, PRE-SWIZZLED for bank-
// conflict-free LDS fragment reads after a LINEAR global_load_lds stage.
//   fcwb[e][h][ d ^ ((h&7)<<3) ] = bf16(fc_w[e][h][d])      (row = 256 B)
//   pjwb[e][d][ (h&~63) | ((h&63) ^ ((d&7)<<3)) ] = bf16(proj_w[e][d][h])
// ---------------------------------------------------------------------------
__global__ __launch_bounds__(256) void moe_conv_w(
    const float* __restrict__ fcw, const float* __restrict__ pjw,
    unsigned short* __restrict__ fcwb, unsigned short* __restrict__ pjwb)
{
    const int id = blockIdx.x * 256 + threadIdx.x;   // 0..131071
    {
        const int base = id * 8;                     // flat idx into [16][512][128]
        const int d0 = base & 127;
        const int h  = (base >> 7) & 511;
        const int dd = d0 ^ ((h & 7) << 3);
        float4 a = *reinterpret_cast<const float4*>(fcw + base);
        float4 b = *reinterpret_cast<const float4*>(fcw + base + 4);
        *reinterpret_cast<uint4*>(fcwb + (base & ~127) + dd) = pack8(a, b);
    }
    {
        const int base = id * 8;                     // flat idx into [16][128][512]
        const int h0 = base & 511;
        const int d  = (base >> 9) & 127;
        const int hh = h0 ^ ((d & 7) << 3);          // stays within 64-chunk
        float4 a = *reinterpret_cast<const float4*>(pjw + base);
        float4 b = *reinterpret_cast<const float4*>(pjw + base + 4);
        *reinterpret_cast<uint4*>(pjwb + (base & ~511) + hh) = pack8(a, b);
    }
}

// ---------------------------------------------------------------------------
// Kernel A v3: gate logits ONLY (fp64-exact products, fp64 accum -> sign).
// Restructured for latency hiding: 16 tokens/block -> grid 1024 (fully
// resident), lane channel-slice = 4 floats (stride-16B LDS reads: 2-way
// bank aliasing = free; stride-16B x loads: fully coalesced).
// fp64 product set identical to previous verified version; only summation
// association differs (error ~1e-15 relative -> decisions unchanged).
// ---------------------------------------------------------------------------
__global__ __launch_bounds__(256) void moe_gate(
    const float* __restrict__ xg,             // [N][2048] fp32
    const float* __restrict__ gw,             // [16][2048] fp32
    const float* __restrict__ gb,             // [16] fp32
    float* __restrict__ gwf)                  // [N][16] float 0/1
{
    __shared__ float gws[16 * 256];           // gate_w chunk, 16 KiB

    const int t  = threadIdx.x;
    const int n0 = blockIdx.x * 16;           // 16 tokens/block
    const int nl = t >> 4;                    // token-local 0..15
    const int p  = t & 15;                    // channel-slice 0..15

    double dacc[16];
#pragma unroll
    for (int e = 0; e < 16; ++e) dacc[e] = 0.0;

    for (int cc = 0; cc < 8; ++cc) {
        __syncthreads();   // protect gws from previous iteration readers
        // stage gate_w chunk [16][256] into LDS (coalesced float4)
#pragma unroll
        for (int ii = 0; ii < 4; ++ii) {
            int fi = ii * 1024 + t * 4;
            int e = fi >> 8, cl = fi & 255;
            *reinterpret_cast<float4*>(&gws[e * 256 + cl]) =
                *reinterpret_cast<const float4*>(gw + (size_t)e * 2048 + cc * 256 + cl);
        }
        __syncthreads();
#pragma unroll
        for (int g = 0; g < 4; ++g) {
            const int cl = g * 64 + p * 4;          // 4-ch slice within 256-chunk
            float4 xa = *reinterpret_cast<const float4*>(
                xg + (size_t)(n0 + nl) * 2048 + cc * 256 + cl);
            double xd0 = xa.x, xd1 = xa.y, xd2 = xa.z, xd3 = xa.w;
#pragma unroll
            for (int e = 0; e < 16; ++e) {
                float4 ga = *reinterpret_cast<const float4*>(&gws[e * 256 + cl]);
                double s = dacc[e];
                s = fma(xd0, (double)ga.x, s);
                s = fma(xd1, (double)ga.y, s);
                s = fma(xd2, (double)ga.z, s);
                s = fma(xd3, (double)ga.w, s);
                dacc[e] = s;
            }
        }
    }
    // reduce over the 16 p-lanes (contiguous lane bits 0..3) via xor-shuffle
#pragma unroll
    for (int e = 0; e < 16; ++e) {
        double v = dacc[e];
        v += __shfl_xor(v, 1);
        v += __shfl_xor(v, 2);
        v += __shfl_xor(v, 4);
        v += __shfl_xor(v, 8);
        dacc[e] = v;
    }
    if (p == 0) {
        float g[16];
#pragma unroll
        for (int e = 0; e < 16; ++e)
            g[e] = (dacc[e] + (double)gb[e] > 0.0) ? 1.0f : 0.0f;
        float4* o = reinterpret_cast<float4*>(gwf + (size_t)(n0 + nl) * 16);
        o[0] = make_float4(g[0],  g[1],  g[2],  g[3]);
        o[1] = make_float4(g[4],  g[5],  g[6],  g[7]);
        o[2] = make_float4(g[8],  g[9],  g[10], g[11]);
        o[3] = make_float4(g[12], g[13], g[14], g[15]);
    }
}

// ---------------------------------------------------------------------------
// Kernel B: per-expert MLP, bf16 MFMA 16x16x32. A-operand gathered DIRECTLY
// from x (4B loads at 64B stride) — the 16 e-blocks sharing a token-block are
// pinned to one XCD (tb-pinned bijective swizzle) so x lines are fetched once
// per XCD L2 and reused 16x.
// PRE=1: pre-converted, pre-swizzled bf16 weights staged via global_load_lds;
//        LDS sized EXACTLY (51200 B) so 3 blocks/CU fit (was 54272 -> 2/CU).
// PRE=0: legacy fp32->bf16 staging (small-workspace fallback, padded LDS).
// ---------------------------------------------------------------------------
template<int PRE>
__global__ __launch_bounds__(256, 2) void moe_expert_mlp(
    const float* __restrict__ xg,             // [N][2048] fp32
    const float* __restrict__ fcw,            // [16][512][128] fp32
    const float* __restrict__ fcb,            // [16][512] fp32
    const float* __restrict__ pjw,            // [16][128][512] fp32
    const float* __restrict__ pjb,            // [16][128] fp32
    const unsigned short* __restrict__ fcwb,  // [16][512][128] bf16 swizzled
    const unsigned short* __restrict__ pjwb,  // [16][128][512] bf16 swizzled
    const float* __restrict__ gwf,            // [N][16]
    float* __restrict__ y)                    // [N][2048] fp32
{
    constexpr int W1S = PRE ? 128 : 136;           // shorts per W1 row
    constexpr int W2S = PRE ? 64  : 72;            // shorts per W2 row
    __shared__ unsigned short W1s[64 * W1S];
    __shared__ unsigned short W2s[128 * W2S];
    __shared__ unsigned short Hs[4 * 32 * 72];     // per-wave [tok_local][hh_local]

    const int t    = threadIdx.x;
    const int wid  = t >> 6;
    const int lane = t & 63;
    const int q    = lane >> 4;
    const int m    = lane & 15;
    // tb-pinned bijective XCD swizzle: raw = (hi:4)(e:4)(lo:3)
    //   XCD = raw&7; e is the fast slot index -> 16 e-blocks of one tb are
    //   consecutive slots on the SAME XCD -> x lines reused 16x in that L2.
    const int raw = blockIdx.x;
    const int e   = (raw >> 3) & 15;
    const int tb  = (raw & 7) | ((raw >> 7) << 3);
    const int n0  = tb * 128 + wid * 32;

    // A fragments for this wave's 32 tokens: A[m=lane&15][k=q*8+j]
    // gathered from x: channel of (e, d) is d*16 + e
    bf16x8 a1[2][4];
#pragma unroll
    for (int tm = 0; tm < 2; ++tm)
#pragma unroll
        for (int kk = 0; kk < 4; ++kk) {
            const float* base = xg + (size_t)(n0 + tm * 16 + m) * 2048
                              + (kk * 32 + q * 8) * 16 + e;
            union { unsigned short u[8]; bf16x8 v; } pk;
#pragma unroll
            for (int j = 0; j < 8; ++j) pk.u[j] = f2bf(base[j * 16]);
            a1[tm][kk] = pk.v;
        }

    f32x4 oacc[2][8];
#pragma unroll
    for (int tm = 0; tm < 2; ++tm)
#pragma unroll
        for (int tn = 0; tn < 8; ++tn) oacc[tm][tn] = (f32x4){0.f, 0.f, 0.f, 0.f};

    unsigned short* HsW = &Hs[wid * 32 * 72];
    const char* W1b = reinterpret_cast<const char*>(W1s);
    const char* W2b = reinterpret_cast<const char*>(W2s);

    for (int hc = 0; hc < 8; ++hc) {
        __syncthreads();   // previous chunk's weight readers done
        if constexpr (PRE) {
            // async linear stage of pre-swizzled bf16 weights (16 KB each)
            const unsigned short* g1 = fcwb + ((size_t)e * 512 + hc * 64) * 128;
            const unsigned short* g2 = pjwb + (size_t)e * 128 * 512 + hc * 64;
#pragma unroll
            for (int it = 0; it < 4; ++it) {
                const int s = it * 2048 + t * 8;
                __builtin_amdgcn_global_load_lds(
                    (const __attribute__((address_space(1))) unsigned int*)(g1 + s),
                    (__attribute__((address_space(3))) unsigned int*)(&W1s[s]), 16, 0, 0);
            }
#pragma unroll
            for (int it = 0; it < 4; ++it) {
                const int s = it * 2048 + t * 8;
                __builtin_amdgcn_global_load_lds(
                    (const __attribute__((address_space(1))) unsigned int*)
                        (g2 + (size_t)(s >> 6) * 512 + (s & 63)),
                    (__attribute__((address_space(3))) unsigned int*)(&W2s[s]), 16, 0, 0);
            }
        } else {
            // legacy: stage fc_w chunk fp32 -> bf16, padded layout
#pragma unroll
            for (int it = 0; it < 4; ++it) {
                int idx = it * 256 + t;
                int hh = idx >> 4, ds = (idx & 15) * 8;
                const float* src = fcw + ((size_t)e * 512 + hc * 64 + hh) * 128 + ds;
                float4 va = *reinterpret_cast<const float4*>(src);
                float4 vb = *reinterpret_cast<const float4*>(src + 4);
                *reinterpret_cast<uint4*>(&W1s[hh * W1S + ds]) = pack8(va, vb);
            }
#pragma unroll
            for (int it = 0; it < 4; ++it) {
                int idx = it * 256 + t;
                int d = idx >> 3, cs = (idx & 7) * 8;
                const float* src = pjw + ((size_t)e * 128 + d) * 512 + hc * 64 + cs;
                float4 va = *reinterpret_cast<const float4*>(src);
                float4 vb = *reinterpret_cast<const float4*>(src + 4);
                *reinterpret_cast<uint4*>(&W2s[d * W2S + cs]) = pack8(va, vb);
            }
        }
        __syncthreads();

        // GEMM1: H1[32 x 64] = Xe[32 x 128] * W1[128 x 64]
        f32x4 h1[2][4];
#pragma unroll
        for (int tm = 0; tm < 2; ++tm)
#pragma unroll
            for (int tn = 0; tn < 4; ++tn) h1[tm][tn] = (f32x4){0.f, 0.f, 0.f, 0.f};
#pragma unroll
        for (int kk = 0; kk < 4; ++kk) {
#pragma unroll
            for (int tn = 0; tn < 4; ++tn) {
                bf16x8 b;
                if constexpr (PRE) {
                    const int r = tn * 16 + m;
                    b = *reinterpret_cast<const bf16x8*>(
                        W1b + r * 256 + (((kk * 32 + q * 8) * 2) ^ ((r & 7) << 4)));
                } else {
                    b = *reinterpret_cast<const bf16x8*>(
                        &W1s[(tn * 16 + m) * W1S + kk * 32 + q * 8]);
                }
                h1[0][tn] = __builtin_amdgcn_mfma_f32_16x16x32_bf16(a1[0][kk], b, h1[0][tn], 0, 0, 0);
                h1[1][tn] = __builtin_amdgcn_mfma_f32_16x16x32_bf16(a1[1][kk], b, h1[1][tn], 0, 0, 0);
            }
        }
        // bias + gelu -> Hs (C/D layout: row = tm*16+q*4+r, col = tn*16+m)
#pragma unroll
        for (int tn = 0; tn < 4; ++tn) {
            float bias = fcb[e * 512 + hc * 64 + tn * 16 + m];
#pragma unroll
            for (int tm = 0; tm < 2; ++tm)
#pragma unroll
                for (int r = 0; r < 4; ++r) {
                    float g = gelu_erf(h1[tm][tn][r] + bias);
                    HsW[(tm * 16 + q * 4 + r) * 72 + tn * 16 + m] = f2bf(g);
                }
        }
        __asm__ volatile("" ::: "memory");  // order Hs writes before A2 reads

        // GEMM2: Oacc[32 x 128] += gelu(H1)[32 x 64] * W2[64 x 128]
#pragma unroll
        for (int kk2 = 0; kk2 < 2; ++kk2) {
            bf16x8 a2_0 = *reinterpret_cast<const bf16x8*>(&HsW[(m) * 72 + kk2 * 32 + q * 8]);
            bf16x8 a2_1 = *reinterpret_cast<const bf16x8*>(&HsW[(16 + m) * 72 + kk2 * 32 + q * 8]);
#pragma unroll
            for (int tn2 = 0; tn2 < 8; ++tn2) {
                bf16x8 b2;
                if constexpr (PRE) {
                    const int r2 = tn2 * 16 + m;
                    b2 = *reinterpret_cast<const bf16x8*>(
                        W2b + r2 * 128 + (((kk2 * 32 + q * 8) * 2) ^ ((r2 & 7) << 4)));
                } else {
                    b2 = *reinterpret_cast<const bf16x8*>(
                        &W2s[(tn2 * 16 + m) * W2S + kk2 * 32 + q * 8]);
                }
                oacc[0][tn2] = __builtin_amdgcn_mfma_f32_16x16x32_bf16(a2_0, b2, oacc[0][tn2], 0, 0, 0);
                oacc[1][tn2] = __builtin_amdgcn_mfma_f32_16x16x32_bf16(a2_1, b2, oacc[1][tn2], 0, 0, 0);
            }
        }
    }

    // epilogue: (acc + proj_b) * gate, store FP32 at y[n][e*128 + d]
    float gwv[2][4];
#pragma unroll
    for (int tm = 0; tm < 2; ++tm)
#pragma unroll
        for (int r = 0; r < 4; ++r)
            gwv[tm][r] = gwf[(size_t)(n0 + tm * 16 + q * 4 + r) * 16 + e];
#pragma unroll
    for (int tn2 = 0; tn2 < 8; ++tn2) {
        float pb = pjb[e * 128 + tn2 * 16 + m];
#pragma unroll
        for (int tm = 0; tm < 2; ++tm)
#pragma unroll
            for (int r = 0; r < 4; ++r) {
                float v = (oacc[tm][tn2][r] + pb) * gwv[tm][r];
                y[(size_t)(n0 + tm * 16 + q * 4 + r) * 2048 + e * 128 + tn2 * 16 + m] = v;
            }
    }
}

extern "C" void kernel_launch(void* const* d_in, const int* in_sizes, int n_in,
                              void* d_out, int out_size, void* d_ws, size_t ws_size,
                              hipStream_t stream) {
    const float* x      = (const float*)d_in[0];
    const float* gate_w = (const float*)d_in[1];
    const float* gate_b = (const float*)d_in[2];
    const float* fc_w   = (const float*)d_in[3];
    const float* fc_b   = (const float*)d_in[4];
    const float* proj_w = (const float*)d_in[5];
    const float* proj_b = (const float*)d_in[6];
    float* y            = (float*)d_out;

    // ws layout: gwf (1 MiB) | fcwb (2 MiB) | pjwb (2 MiB)
    const size_t gwf_bytes = (size_t)N_TOK * E_NUM * 4;
    const size_t wb_bytes  = (size_t)E_NUM * H_DIM * DE_DIM * 2;
    float* gwf = (float*)d_ws;
    unsigned short* fcwb = (unsigned short*)((char*)d_ws + gwf_bytes);
    unsigned short* pjwb = (unsigned short*)((char*)d_ws + gwf_bytes + wb_bytes);
    const int use_pre = (ws_size >= gwf_bytes + 2 * wb_bytes) ? 1 : 0;

    if (use_pre)
        moe_conv_w<<<dim3(512), dim3(256), 0, stream>>>(fc_w, proj_w, fcwb, pjwb);
    moe_gate<<<dim3(N_TOK / 16), dim3(256), 0, stream>>>(x, gate_w, gate_b, gwf);
    if (use_pre)
        moe_expert_mlp<1><<<dim3(E_NUM * (N_TOK / 128)), dim3(256), 0, stream>>>(
            x, fc_w, fc_b, proj_w, proj_b, fcwb, pjwb, gwf, y);
    else
        moe_expert_mlp<0><<<dim3(E_NUM * (N_TOK / 128)), dim3(256), 0, stream>>>(
            x, fc_w, fc_b, proj_w, proj_b, fcwb, pjwb, gwf, y);
}